// Round 12
// baseline (345.968 us; speedup 1.0000x reference)
//
#include <hip/hip_runtime.h>

#define NN 100000
#define NE 1600000
#define DIM0 11
#define H 128
#define NL 4
#define NG 4096
#define EPS 1e-5f

#define NBKT 391       // buckets of 256 nodes: bucket = dst >> 8
#define CAP 5120       // fixed bucket capacity (mean 4096, sigma 64 -> 16 sigma)
#define SUBCAP 1280    // per-64-node sub-region of col (mean 1024 + 8 sigma)
#define EPB 2048       // edges per block in scatter phase
static constexpr int NBB = (NE + EPB - 1) / EPB;  // 782
#define PREP_B 32
#define RANGE_B 391    // (NN+255)/256
static constexpr int FRONT_B = PREP_B + RANGE_B + NBB + NN / 16;  // 32+391+782+6250

typedef _Float16 f16x8 __attribute__((ext_vector_type(8)));
typedef float f32x4 __attribute__((ext_vector_type(4)));
typedef float f32x2 __attribute__((ext_vector_type(2)));

// r24 results: L3 atomic fix + front-end fusion -> 343us. Remainder ~115us,
// prime suspect k_bcsr: 391 blocks = 1.5/CU, 60% of CUs idle on a ~58MB
// serial chain. r25 (this round): 4 sub-blocks per bucket (grid 1564,
// 6.1/CU). Sub-block owns 64 nodes; filter-scans bucket ebuf (L2-resident
// re-read), 64-entry scan, scatters into PRIVATE col region (bucket*CAP +
// sub*1280) so no cross-sub prefix; rps/rpe absolute -> k_layer untouched.
// bscatter/bfill untouched (bucket-64 there would mean ~900K global atomics
// on 6KB = r5's convicted cross-XCD mechanism).
// k_layer phase 1 = FROZEN r20 optimum (57.6us = random-gather fabric rate).

// ---- fp8 helpers (OCP e4m3 on gfx950) ----

__device__ __forceinline__ uint2 pack_fp8x8(const float* v) {
    int lo = 0, hi = 0;
    lo = __builtin_amdgcn_cvt_pk_fp8_f32(v[0], v[1], lo, false);
    lo = __builtin_amdgcn_cvt_pk_fp8_f32(v[2], v[3], lo, true);
    hi = __builtin_amdgcn_cvt_pk_fp8_f32(v[4], v[5], hi, false);
    hi = __builtin_amdgcn_cvt_pk_fp8_f32(v[6], v[7], hi, true);
    return (uint2){(unsigned)lo, (unsigned)hi};
}

__device__ __forceinline__ void acc_fp8x8(uint2 u, f32x2* a2) {
    a2[0] += __builtin_amdgcn_cvt_pk_f32_fp8((int)u.x, false);
    a2[1] += __builtin_amdgcn_cvt_pk_f32_fp8((int)u.x, true);
    a2[2] += __builtin_amdgcn_cvt_pk_f32_fp8((int)u.y, false);
    a2[3] += __builtin_amdgcn_cvt_pk_f32_fp8((int)u.y, true);
}

// ---------------- front: Wpack + out-init | range | bscatter | embed-hh ----------------

__global__ __launch_bounds__(256) void k_front(const float* __restrict__ W, _Float16* __restrict__ Wp,
                                               float* __restrict__ out, const float* __restrict__ bout,
                                               const int* __restrict__ batch, int* __restrict__ gstart,
                                               int* __restrict__ gend,
                                               const int* __restrict__ src, const int* __restrict__ dst,
                                               int* __restrict__ bfill, unsigned int* __restrict__ ebuf,
                                               const float* __restrict__ x, const float* __restrict__ We,
                                               const float* __restrict__ be, _Float16* __restrict__ hh) {
    __shared__ int lc[NBKT];
    __shared__ int lbase[NBKT];
    __shared__ float Ws[DIM0 * H];
    __shared__ float bs[H];
    __shared__ float xs[16 * DIM0];
    int bb = blockIdx.x;
    int t = threadIdx.x;

    if (bb < PREP_B) {
        // ---- prep: out init + W pack (8192 threads) ----
        int i = bb * 256 + t;
        if (i < NG) out[i] = bout[0];
        int lane = i & 63;
        int idx = i >> 6;          // 0..127
        int nt = idx & 7;
        int ks = (idx >> 3) & 3;
        int l = idx >> 5;
        int q = lane >> 4, l15 = lane & 15;
        const float* Wl = W + (size_t)l * H * H;
        _Float16* o = Wp + (size_t)idx * 512 + lane * 8;
#pragma unroll
        for (int j = 0; j < 8; j++)
            o[j] = (_Float16)(Wl[(ks * 32 + q * 8 + j) * H + nt * 16 + l15]);
    } else if (bb < PREP_B + RANGE_B) {
        // ---- range: batch sorted -> boundary stores, no atomics ----
        int n = (bb - PREP_B) * 256 + t;
        if (n < NN) {
            int g = batch[n];
            if (n == 0) {
                gstart[g] = 0;
            } else {
                int gp = batch[n - 1];
                if (gp != g) { gstart[g] = n; gend[gp] = n; }
            }
            if (n == NN - 1) gend[g] = NN;
        }
    } else if (bb < PREP_B + RANGE_B + NBB) {
        // ---- bscatter ----
        for (int i = t; i < NBKT; i += 256) lc[i] = 0;
        __syncthreads();
        int base = (bb - PREP_B - RANGE_B) * EPB;
        int rank[8];
        int bk[8];
        unsigned pk[8];
#pragma unroll
        for (int i = 0; i < 8; i++) {
            int e = base + i * 256 + t;
            if (e < NE) {
                int d = dst[e];
                int s = src[e];
                int b = d >> 8;
                bk[i] = b;
                pk[i] = (unsigned)s | ((unsigned)(d & 255) << 17);
                rank[i] = atomicAdd(&lc[b], 1);
            } else bk[i] = -1;
        }
        __syncthreads();
        for (int i = t; i < NBKT; i += 256)
            lbase[i] = i * CAP + (lc[i] ? atomicAdd(&bfill[i], lc[i]) : 0);
        __syncthreads();
#pragma unroll
        for (int i = 0; i < 8; i++) {
            if (bk[i] >= 0)
                ebuf[lbase[bk[i]] + rank[i]] = pk[i];
        }
    } else {
        // ---- embed: hh = fp16(relu(x @ We + be)) only (no dis dependency) ----
        int eb = bb - PREP_B - RANGE_B - NBB;
        for (int i = t; i < DIM0 * H; i += 256) Ws[i] = We[i];
        if (t < H) bs[t] = be[t];
        if (t < 16 * DIM0) xs[t] = x[(size_t)eb * (16 * DIM0) + t];
        __syncthreads();
        int nl = t >> 4;
        int node = eb * 16 + nl;
        int l4 = t & 15;
        f16x8 o;
#pragma unroll
        for (int j = 0; j < 8; j++) {
            int c = l4 * 8 + j;
            float acc = bs[c];
#pragma unroll
            for (int k = 0; k < DIM0; k++) acc += xs[nl * DIM0 + k] * Ws[k * H + c];
            o[j] = (_Float16)fmaxf(acc, 0.f);
        }
        *(f16x8*)&hh[(size_t)node * H + l4 * 8] = o;
    }
}

// ---------------- CSR pass 2 + fp8 hp pack: 4 sub-blocks per bucket ----------------
// Sub-block owns 64 nodes. Filter-scan bucket ebuf (L2-resident) -> count,
// 64-entry scan, scatter to private col region bucket*CAP + sub*SUBCAP,
// write dis/rps/rpe, pack hp = fp8(hh * dis) for its nodes.

__global__ __launch_bounds__(256) void k_bcsr(const unsigned int* __restrict__ ebuf,
                                              const int* __restrict__ bfill,
                                              int* __restrict__ rps, int* __restrict__ rpe,
                                              int* __restrict__ col, float* __restrict__ dis,
                                              const _Float16* __restrict__ hh, uint2* __restrict__ hp) {
    __shared__ int lcnt[64];
    __shared__ int lfill[64];
    __shared__ int tmp[64];
    __shared__ float dnsh[64];
    int t = threadIdx.x;
    int b = blockIdx.x >> 2;        // bucket
    int sub = blockIdx.x & 3;       // 64-node sub-range
    int cb = b * CAP;
    int base = cb + sub * SUBCAP;   // private col region
    int ecnt = bfill[b];
    int n0 = (b << 8) + (sub << 6);
    int nb2 = min(64, NN - n0);
    if (nb2 <= 0) return;           // uniform per block

    if (t < 64) { lcnt[t] = 0; lfill[t] = 0; }
    __syncthreads();

    for (int i = t; i < ecnt; i += 256) {
        unsigned p = ebuf[cb + i];
        int dl = (int)(p >> 17);
        if ((dl >> 6) == sub) atomicAdd(&lcnt[dl & 63], 1);
    }
    __syncthreads();

    int cnt = (t < 64) ? lcnt[t] : 0;
    if (t < nb2) {
        float dnv = rsqrtf((float)(cnt + 1));
        dnsh[t] = dnv;
        dis[n0 + t] = dnv;
    }
    if (t < 64) tmp[t] = cnt;
    __syncthreads();
#pragma unroll
    for (int off = 1; off < 64; off <<= 1) {
        int x = (t >= off && t < 64) ? tmp[t - off] : 0;
        __syncthreads();
        if (t < 64) tmp[t] += x;
        __syncthreads();
    }
    if (t < 64) {
        int incl = tmp[t];
        lcnt[t] = incl - cnt;       // exclusive prefix (scatter offsets)
        if (t < nb2) {
            rps[n0 + t] = base + incl - cnt;
            rpe[n0 + t] = base + incl;
        }
    }
    __syncthreads();

    for (int i = t; i < ecnt; i += 256) {
        unsigned p = ebuf[cb + i];
        int dl = (int)(p >> 17);
        if ((dl >> 6) == sub) {
            int j = dl & 63;
            col[base + lcnt[j] + atomicAdd(&lfill[j], 1)] = (int)(p & 0x1FFFFu);
        }
    }

    __syncthreads();
    // fp8 pre-scaled gather copy for this sub-block's nodes
    const f16x8* hh8 = (const f16x8*)hh;
    for (int idx = t; idx < nb2 * 16; idx += 256) {
        int nl = idx >> 4, l4 = idx & 15;
        f16x8 h8 = hh8[(size_t)(n0 + nl) * 16 + l4];
        float dn = dnsh[nl];
        float hv[8];
#pragma unroll
        for (int j = 0; j < 8; j++) hv[j] = (float)h8[j] * dn;
        hp[(size_t)(n0 + nl) * 16 + l4] = pack_fp8x8(hv);
    }
}

// ---------------- fused layer: hout = relu(LN(agg(hin) @ W + b)) + hin ----------------
// Phase 1 = FROZEN r20 optimum. Epilogue mode 1: store hout + fp8 copy.
// Mode 0 (last layer): fused mean-pool via segmented wave reduction --
// segment-tail lanes only do atomicAdd (sorted batch -> ascending g).

__global__ __launch_bounds__(128, 8) void k_layer(const _Float16* __restrict__ hin,
                                                  _Float16* __restrict__ hout,
                                                  const uint2* __restrict__ hpin,
                                                  uint2* __restrict__ hpout,
                                                  const float* __restrict__ dis, const int* __restrict__ rps,
                                                  const int* __restrict__ rpe, const int* __restrict__ col,
                                                  const _Float16* __restrict__ Wp,
                                                  const float* __restrict__ bias,
                                                  const float* __restrict__ gamma,
                                                  const float* __restrict__ beta,
                                                  const int* __restrict__ batch,
                                                  const int* __restrict__ gstart,
                                                  const int* __restrict__ gend,
                                                  const float* __restrict__ Wout,
                                                  float* __restrict__ out,
                                                  int store_hp) {
    __shared__ _Float16 Ls[2][16][136];   // 8704 B
    int tid = threadIdx.x;
    int wave = tid >> 6;
    int lane = tid & 63;
    int q = lane >> 4, l4 = lane & 15;
    int nbase = blockIdx.x * 32 + wave * 16;   // 32 | NN, no tail

    // wave-wide prefetch of the 16 nodes' CSR ranges + dis
    int l16 = lane & 15;
    int ev0 = rps[nbase + l16];
    int ev1 = rpe[nbase + l16];
    float dv = dis[nbase + l16];

    // ---- phase 1: gather 16 nodes into Ls, 4 nodes per round ----
#pragma unroll 1
    for (int r = 0; r < 4; r++) {
        int nl = r * 4 + q;                 // node slot owned by this quarter
        int e0 = __shfl(ev0, nl, 64);
        int e1 = __shfl(ev1, nl, 64);
        float dn = __shfl(dv, nl, 64);
        int node = nbase + nl;

        f32x2 a2[4];
#pragma unroll
        for (int j = 0; j < 4; j++) a2[j] = (f32x2){0.f, 0.f};

        uint2 sv = hpin[(size_t)node * 16 + l4];   // self row, issued early

        int e = e0;
        int pc0 = 0, pc1 = 0, pc2 = 0, pc3 = 0;
        if (e < e1) {                       // prime col pipeline (clamped)
            int m = e1 - 1;
            pc0 = col[e];
            pc1 = col[(e + 1 < e1) ? e + 1 : m];
            pc2 = col[(e + 2 < e1) ? e + 2 : m];
            pc3 = col[(e + 3 < e1) ? e + 3 : m];
        }
#pragma unroll 1
        for (; e + 3 < e1; e += 4) {
            int s0 = pc0, s1 = pc1, s2 = pc2, s3 = pc3;
            int n0 = e + 4, n1 = e + 5, n2 = e + 6, n3 = e + 7;
            pc0 = col[(n0 < e1) ? n0 : e0];   // next-iter cols overlap row loads
            pc1 = col[(n1 < e1) ? n1 : e0];
            pc2 = col[(n2 < e1) ? n2 : e0];
            pc3 = col[(n3 < e1) ? n3 : e0];
            uint2 v0 = hpin[(size_t)s0 * 16 + l4];
            uint2 v1 = hpin[(size_t)s1 * 16 + l4];
            uint2 v2 = hpin[(size_t)s2 * 16 + l4];
            uint2 v3 = hpin[(size_t)s3 * 16 + l4];
            acc_fp8x8(v0, a2);
            acc_fp8x8(v1, a2);
            acc_fp8x8(v2, a2);
            acc_fp8x8(v3, a2);
        }
        // tail (<=3 edges): cols already prefetched
        int k = e1 - e;
        if (k > 0) { uint2 v = hpin[(size_t)pc0 * 16 + l4]; acc_fp8x8(v, a2); }
        if (k > 1) { uint2 v = hpin[(size_t)pc1 * 16 + l4]; acc_fp8x8(v, a2); }
        if (k > 2) { uint2 v = hpin[(size_t)pc2 * 16 + l4]; acc_fp8x8(v, a2); }

        acc_fp8x8(sv, a2);   // self-loop

        f16x8 o;
#pragma unroll
        for (int j = 0; j < 4; j++) {
            o[2 * j]     = (_Float16)(a2[j][0] * dn);
            o[2 * j + 1] = (_Float16)(a2[j][1] * dn);
        }
        *(f16x8*)&Ls[wave][nl][l4 * 8] = o;
    }

    // ---- phase 2: read A-fragments into registers, then GEMM + LN (Ls reused) ----
    f16x8 af[4];
#pragma unroll
    for (int ks = 0; ks < 4; ks++)
        af[ks] = *(const f16x8*)&Ls[wave][l4][ks * 32 + q * 8];

    float bb[8], gm[8], bt[8];
#pragma unroll
    for (int nt = 0; nt < 8; nt++) {
        bb[nt] = bias[nt * 16 + l4];
        gm[nt] = gamma[nt * 16 + l4];
        bt[nt] = beta[nt * 16 + l4];
    }

    const f16x8* wp8 = (const f16x8*)Wp;
    f32x4 acc[8];
#pragma unroll
    for (int nt = 0; nt < 8; nt++) {
        acc[nt] = (f32x4){0.f, 0.f, 0.f, 0.f};
#pragma unroll
        for (int ks = 0; ks < 4; ks++) {
            f16x8 bf = wp8[(ks * 8 + nt) * 64 + lane];
            acc[nt] = __builtin_amdgcn_mfma_f32_16x16x32_f16(af[ks], bf, acc[nt], 0, 0, 0);
        }
#pragma unroll
        for (int r = 0; r < 4; r++) acc[nt][r] += bb[nt];
    }

    float mu[4], rs[4];
#pragma unroll
    for (int r = 0; r < 4; r++) {
        float s = 0.f;
#pragma unroll
        for (int nt = 0; nt < 8; nt++) s += acc[nt][r];
#pragma unroll
        for (int off = 8; off > 0; off >>= 1) s += __shfl_xor(s, off, 64);
        mu[r] = s * (1.f / 128.f);
    }
#pragma unroll
    for (int r = 0; r < 4; r++) {
        float v = 0.f;
#pragma unroll
        for (int nt = 0; nt < 8; nt++) {
            float d = acc[nt][r] - mu[r];
            v += d * d;
        }
#pragma unroll
        for (int off = 8; off > 0; off >>= 1) v += __shfl_xor(v, off, 64);
        rs[r] = rsqrtf(v * (1.f / 128.f) + EPS);
    }

    // overwrite Ls with LN output (af already in registers)
#pragma unroll
    for (int nt = 0; nt < 8; nt++)
#pragma unroll
        for (int r = 0; r < 4; r++) {
            float o = fmaxf((acc[nt][r] - mu[r]) * rs[r] * gm[nt] + bt[nt], 0.f);
            Ls[wave][q * 4 + r][nt * 16 + l4] = (_Float16)o;
        }

    // epilogue
    const f16x8* hi8 = (const f16x8*)hin;
    f16x8* ho8 = (f16x8*)hout;
    int ck = lane & 15;
    if (store_hp) {
#pragma unroll
        for (int it = 0; it < 4; it++) {
            int c = it * 64 + lane;
            int rr = c >> 4;
            int row = nbase + rr;
            f16x8 ln = *(const f16x8*)&Ls[wave][rr][ck * 8];
            f16x8 res = hi8[(size_t)row * 16 + ck];
            float dn2 = __shfl(dv, rr, 64);
            f16x8 o;
            float hv[8];
#pragma unroll
            for (int j = 0; j < 8; j++) {
                float s = (float)ln[j] + (float)res[j];
                o[j] = (_Float16)s;
                hv[j] = s * dn2;
            }
            ho8[(size_t)row * 16 + ck] = o;
            hpout[(size_t)row * 16 + ck] = pack_fp8x8(hv);
        }
    } else {
        // fused global-mean-pool with segmented wave reduction
        float wv[8];
#pragma unroll
        for (int j = 0; j < 8; j++) wv[j] = Wout[ck * 8 + j];
        float pv[4];
#pragma unroll
        for (int it = 0; it < 4; it++) {
            int c = it * 64 + lane;
            int rr = c >> 4;
            int row = nbase + rr;
            f16x8 ln = *(const f16x8*)&Ls[wave][rr][ck * 8];
            f16x8 res = hi8[(size_t)row * 16 + ck];
            float p = 0.f;
#pragma unroll
            for (int j = 0; j < 8; j++)
                p += ((float)ln[j] + (float)res[j]) * wv[j];
            p += __shfl_xor(p, 1, 64);
            p += __shfl_xor(p, 2, 64);
            p += __shfl_xor(p, 4, 64);
            p += __shfl_xor(p, 8, 64);
            pv[it] = p;   // replicated across the 16-lane quarter
        }
        // redistribute: lane l16 takes row l16's value (src lane (l16&3)*16, slot l16>>2)
        int srcl = (l16 & 3) << 4;
        float s0 = __shfl(pv[0], srcl, 64);
        float s1 = __shfl(pv[1], srcl, 64);
        float s2 = __shfl(pv[2], srcl, 64);
        float s3 = __shfl(pv[3], srcl, 64);
        float v = (l16 < 4) ? s0 : (l16 < 8) ? s1 : (l16 < 12) ? s2 : s3;
        int g = batch[nbase + l16];
        // segmented inclusive sum (g ascending over rows; 16-lane groups)
#pragma unroll
        for (int off = 1; off < 16; off <<= 1) {
            float vn = __shfl(v, lane - off, 64);
            int gn = __shfl(g, lane - off, 64);
            if (l16 >= off && gn == g) v += vn;
        }
        int gnx = __shfl(g, lane + 1, 64);
        if (lane < 16 && ((l16 == 15) || (gnx != g))) {
            float inv = 1.f / (float)max(gend[g] - gstart[g], 1);
            atomicAdd(&out[g], v * inv);
        }
    }
}

// ---------------- launcher ----------------

extern "C" void kernel_launch(void* const* d_in, const int* in_sizes, int n_in,
                              void* d_out, int out_size, void* d_ws, size_t ws_size,
                              hipStream_t stream) {
    const float* x       = (const float*)d_in[0];
    const int*   edge    = (const int*)d_in[1];
    const int*   batch   = (const int*)d_in[2];
    const float* W_embed = (const float*)d_in[3];
    const float* b_embed = (const float*)d_in[4];
    const float* W_gnn   = (const float*)d_in[5];
    const float* b_gnn   = (const float*)d_in[6];
    const float* gamma   = (const float*)d_in[7];
    const float* beta    = (const float*)d_in[8];
    const float* W_out   = (const float*)d_in[9];
    const float* b_out   = (const float*)d_in[10];
    float* out = (float*)d_out;

    char* ws = (char*)d_ws;
    size_t off = 0;
    auto alloc = [&](size_t bytes) -> char* {
        char* p = ws + off;
        off += (bytes + 255) & ~(size_t)255;
        return p;
    };
    _Float16*     hh0  = (_Float16*)alloc((size_t)NN * H * 2);
    _Float16*     hh1  = (_Float16*)alloc((size_t)NN * H * 2);
    uint2*        hp0  = (uint2*)alloc((size_t)NN * H);       // fp8 gather copies
    uint2*        hp1  = (uint2*)alloc((size_t)NN * H);
    _Float16*     Wp   = (_Float16*)alloc((size_t)NL * 4 * 8 * 512 * 2);
    float*        dis  = (float*)alloc((size_t)NN * 4);
    int*          rps  = (int*)alloc((size_t)NN * 4);
    int*          rpe  = (int*)alloc((size_t)NN * 4);
    int*          col  = (int*)alloc((size_t)NBKT * CAP * 4);
    unsigned int* ebuf = (unsigned int*)alloc((size_t)NBKT * CAP * 4);
    int*          bfill = (int*)alloc((NBKT + 1) * 4);
    int*   gstart = (int*)alloc((size_t)NG * 4);
    int*   gend   = (int*)alloc((size_t)NG * 4);

    const int* srcp = edge;
    const int* dstp = edge + NE;

    hipMemsetAsync(bfill, 0, (NBKT + 1) * sizeof(int), stream);
    k_front<<<FRONT_B, 256, 0, stream>>>(W_gnn, Wp, out, b_out,
                                         batch, gstart, gend,
                                         srcp, dstp, bfill, ebuf,
                                         x, W_embed, b_embed, hh0);
    k_bcsr<<<NBKT * 4, 256, 0, stream>>>(ebuf, bfill, rps, rpe, col, dis, hh0, hp0);

    // ping-pong: L0 hh0->hh1, L1 hh1->hh0, L2 hh0->hh1, L3 fused-pool -> out
    _Float16* hb[2] = {hh0, hh1};
    uint2*    hp[2] = {hp0, hp1};
    for (int l = 0; l < NL; l++) {
        k_layer<<<(NN + 31) / 32, 128, 0, stream>>>(hb[l & 1], hb[(l & 1) ^ 1],
                                                    hp[l & 1], hp[(l & 1) ^ 1],
                                                    dis, rps, rpe, col,
                                                    Wp + (size_t)l * 4 * 8 * 512,
                                                    b_gnn + l * H, gamma + l * H, beta + l * H,
                                                    batch, gstart, gend, W_out, out,
                                                    (l != NL - 1) ? 1 : 0);
    }
}

// Round 13
// 342.181 us; speedup vs baseline: 1.0111x; 1.0111x over previous
//
#include <hip/hip_runtime.h>

#define NN 100000
#define NE 1600000
#define DIM0 11
#define H 128
#define NL 4
#define NG 4096
#define EPS 1e-5f

#define NBKT 391       // buckets of 256 nodes: bucket = dst >> 8
#define CAP 5120       // fixed bucket capacity (mean 4096, sigma 64 -> 16 sigma)
#define SUBCAP 1280    // per-64-node sub-region of col (mean 1024 + 8 sigma)
#define EPB 4096       // edges per block in scatter phase (r26: back to r3 config)
static constexpr int NBB = (NE + EPB - 1) / EPB;  // 391
#define PREP_B 32
#define RANGE_B 391    // (NN+255)/256
static constexpr int FRONT_B = PREP_B + RANGE_B + NBB + NN / 16;  // 32+391+391+6250

typedef _Float16 f16x8 __attribute__((ext_vector_type(8)));
typedef float f32x4 __attribute__((ext_vector_type(4)));
typedef float f32x2 __attribute__((ext_vector_type(2)));

// r25: k_bcsr split neutral -> k_bcsr was minor. Re-derived k_layer regime:
// 104MB/56us = 3.4x above the 16us pure-BW floor, HBM 39% -> NOT a fabric
// throughput wall; a VMEM-queue concurrency wall (entries are instructions).
// r26 (this round): phase 1 regroup 4x16-lane quarters -> 8x8-lane groups,
// lane loads uint4: ONE load instruction covers 8 rows (1KB) vs 4 rows
// (512B). 2-deep per group keeps the SAME 16-row random window (r17/r22
// inflation mechanism avoided) in HALF the queue entries. hp bytes + Ls
// layout unchanged -> producers, phase 2, epilogue untouched.
// Bound (128,8)->(128,6): regs ~50-60, avoid spill. EPB 2048->4096: halves
// global bfill atomic count (r19's unmeasured doubling reverted).

// ---- fp8 helpers (OCP e4m3 on gfx950) ----

__device__ __forceinline__ uint2 pack_fp8x8(const float* v) {
    int lo = 0, hi = 0;
    lo = __builtin_amdgcn_cvt_pk_fp8_f32(v[0], v[1], lo, false);
    lo = __builtin_amdgcn_cvt_pk_fp8_f32(v[2], v[3], lo, true);
    hi = __builtin_amdgcn_cvt_pk_fp8_f32(v[4], v[5], hi, false);
    hi = __builtin_amdgcn_cvt_pk_fp8_f32(v[6], v[7], hi, true);
    return (uint2){(unsigned)lo, (unsigned)hi};
}

__device__ __forceinline__ void acc_fp8x16(uint4 u, f32x2* a2) {
    a2[0] += __builtin_amdgcn_cvt_pk_f32_fp8((int)u.x, false);
    a2[1] += __builtin_amdgcn_cvt_pk_f32_fp8((int)u.x, true);
    a2[2] += __builtin_amdgcn_cvt_pk_f32_fp8((int)u.y, false);
    a2[3] += __builtin_amdgcn_cvt_pk_f32_fp8((int)u.y, true);
    a2[4] += __builtin_amdgcn_cvt_pk_f32_fp8((int)u.z, false);
    a2[5] += __builtin_amdgcn_cvt_pk_f32_fp8((int)u.z, true);
    a2[6] += __builtin_amdgcn_cvt_pk_f32_fp8((int)u.w, false);
    a2[7] += __builtin_amdgcn_cvt_pk_f32_fp8((int)u.w, true);
}

// ---------------- front: Wpack + out-init | range | bscatter | embed-hh ----------------

__global__ __launch_bounds__(256) void k_front(const float* __restrict__ W, _Float16* __restrict__ Wp,
                                               float* __restrict__ out, const float* __restrict__ bout,
                                               const int* __restrict__ batch, int* __restrict__ gstart,
                                               int* __restrict__ gend,
                                               const int* __restrict__ src, const int* __restrict__ dst,
                                               int* __restrict__ bfill, unsigned int* __restrict__ ebuf,
                                               const float* __restrict__ x, const float* __restrict__ We,
                                               const float* __restrict__ be, _Float16* __restrict__ hh) {
    __shared__ int lc[NBKT];
    __shared__ int lbase[NBKT];
    __shared__ float Ws[DIM0 * H];
    __shared__ float bs[H];
    __shared__ float xs[16 * DIM0];
    int bb = blockIdx.x;
    int t = threadIdx.x;

    if (bb < PREP_B) {
        // ---- prep: out init + W pack (8192 threads) ----
        int i = bb * 256 + t;
        if (i < NG) out[i] = bout[0];
        int lane = i & 63;
        int idx = i >> 6;          // 0..127
        int nt = idx & 7;
        int ks = (idx >> 3) & 3;
        int l = idx >> 5;
        int q = lane >> 4, l15 = lane & 15;
        const float* Wl = W + (size_t)l * H * H;
        _Float16* o = Wp + (size_t)idx * 512 + lane * 8;
#pragma unroll
        for (int j = 0; j < 8; j++)
            o[j] = (_Float16)(Wl[(ks * 32 + q * 8 + j) * H + nt * 16 + l15]);
    } else if (bb < PREP_B + RANGE_B) {
        // ---- range: batch sorted -> boundary stores, no atomics ----
        int n = (bb - PREP_B) * 256 + t;
        if (n < NN) {
            int g = batch[n];
            if (n == 0) {
                gstart[g] = 0;
            } else {
                int gp = batch[n - 1];
                if (gp != g) { gstart[g] = n; gend[gp] = n; }
            }
            if (n == NN - 1) gend[g] = NN;
        }
    } else if (bb < PREP_B + RANGE_B + NBB) {
        // ---- bscatter (EPB 4096, 16 edges/thread) ----
        for (int i = t; i < NBKT; i += 256) lc[i] = 0;
        __syncthreads();
        int base = (bb - PREP_B - RANGE_B) * EPB;
        int rank[16];
        int bk[16];
        unsigned pk[16];
#pragma unroll
        for (int i = 0; i < 16; i++) {
            int e = base + i * 256 + t;
            if (e < NE) {
                int d = dst[e];
                int s = src[e];
                int b = d >> 8;
                bk[i] = b;
                pk[i] = (unsigned)s | ((unsigned)(d & 255) << 17);
                rank[i] = atomicAdd(&lc[b], 1);
            } else bk[i] = -1;
        }
        __syncthreads();
        for (int i = t; i < NBKT; i += 256)
            lbase[i] = i * CAP + (lc[i] ? atomicAdd(&bfill[i], lc[i]) : 0);
        __syncthreads();
#pragma unroll
        for (int i = 0; i < 16; i++) {
            if (bk[i] >= 0)
                ebuf[lbase[bk[i]] + rank[i]] = pk[i];
        }
    } else {
        // ---- embed: hh = fp16(relu(x @ We + be)) only (no dis dependency) ----
        int eb = bb - PREP_B - RANGE_B - NBB;
        for (int i = t; i < DIM0 * H; i += 256) Ws[i] = We[i];
        if (t < H) bs[t] = be[t];
        if (t < 16 * DIM0) xs[t] = x[(size_t)eb * (16 * DIM0) + t];
        __syncthreads();
        int nl = t >> 4;
        int node = eb * 16 + nl;
        int l4 = t & 15;
        f16x8 o;
#pragma unroll
        for (int j = 0; j < 8; j++) {
            int c = l4 * 8 + j;
            float acc = bs[c];
#pragma unroll
            for (int k = 0; k < DIM0; k++) acc += xs[nl * DIM0 + k] * Ws[k * H + c];
            o[j] = (_Float16)fmaxf(acc, 0.f);
        }
        *(f16x8*)&hh[(size_t)node * H + l4 * 8] = o;
    }
}

// ---------------- CSR pass 2 + fp8 hp pack: 4 sub-blocks per bucket ----------------

__global__ __launch_bounds__(256) void k_bcsr(const unsigned int* __restrict__ ebuf,
                                              const int* __restrict__ bfill,
                                              int* __restrict__ rps, int* __restrict__ rpe,
                                              int* __restrict__ col, float* __restrict__ dis,
                                              const _Float16* __restrict__ hh, uint2* __restrict__ hp) {
    __shared__ int lcnt[64];
    __shared__ int lfill[64];
    __shared__ int tmp[64];
    __shared__ float dnsh[64];
    int t = threadIdx.x;
    int b = blockIdx.x >> 2;        // bucket
    int sub = blockIdx.x & 3;       // 64-node sub-range
    int cb = b * CAP;
    int base = cb + sub * SUBCAP;   // private col region
    int ecnt = bfill[b];
    int n0 = (b << 8) + (sub << 6);
    int nb2 = min(64, NN - n0);
    if (nb2 <= 0) return;           // uniform per block

    if (t < 64) { lcnt[t] = 0; lfill[t] = 0; }
    __syncthreads();

    for (int i = t; i < ecnt; i += 256) {
        unsigned p = ebuf[cb + i];
        int dl = (int)(p >> 17);
        if ((dl >> 6) == sub) atomicAdd(&lcnt[dl & 63], 1);
    }
    __syncthreads();

    int cnt = (t < 64) ? lcnt[t] : 0;
    if (t < nb2) {
        float dnv = rsqrtf((float)(cnt + 1));
        dnsh[t] = dnv;
        dis[n0 + t] = dnv;
    }
    if (t < 64) tmp[t] = cnt;
    __syncthreads();
#pragma unroll
    for (int off = 1; off < 64; off <<= 1) {
        int x = (t >= off && t < 64) ? tmp[t - off] : 0;
        __syncthreads();
        if (t < 64) tmp[t] += x;
        __syncthreads();
    }
    if (t < 64) {
        int incl = tmp[t];
        lcnt[t] = incl - cnt;       // exclusive prefix (scatter offsets)
        if (t < nb2) {
            rps[n0 + t] = base + incl - cnt;
            rpe[n0 + t] = base + incl;
        }
    }
    __syncthreads();

    for (int i = t; i < ecnt; i += 256) {
        unsigned p = ebuf[cb + i];
        int dl = (int)(p >> 17);
        if ((dl >> 6) == sub) {
            int j = dl & 63;
            col[base + lcnt[j] + atomicAdd(&lfill[j], 1)] = (int)(p & 0x1FFFFu);
        }
    }

    __syncthreads();
    // fp8 pre-scaled gather copy for this sub-block's nodes
    const f16x8* hh8 = (const f16x8*)hh;
    for (int idx = t; idx < nb2 * 16; idx += 256) {
        int nl = idx >> 4, l4 = idx & 15;
        f16x8 h8 = hh8[(size_t)(n0 + nl) * 16 + l4];
        float dn = dnsh[nl];
        float hv[8];
#pragma unroll
        for (int j = 0; j < 8; j++) hv[j] = (float)h8[j] * dn;
        hp[(size_t)(n0 + nl) * 16 + l4] = pack_fp8x8(hv);
    }
}

// ---------------- fused layer: hout = relu(LN(agg(hin) @ W + b)) + hin ----------------
// Phase 1 (r26): 8x8-lane groups; group owns a node (2 rounds x 8 nodes);
// lane loads uint4 -> one instruction = 8 rows (1KB), 2-deep per group keeps
// the 16-row window. Phase 2 + epilogue unchanged. Mode 0 = fused pool.

__global__ __launch_bounds__(128, 6) void k_layer(const _Float16* __restrict__ hin,
                                                  _Float16* __restrict__ hout,
                                                  const uint2* __restrict__ hpin,
                                                  uint2* __restrict__ hpout,
                                                  const float* __restrict__ dis, const int* __restrict__ rps,
                                                  const int* __restrict__ rpe, const int* __restrict__ col,
                                                  const _Float16* __restrict__ Wp,
                                                  const float* __restrict__ bias,
                                                  const float* __restrict__ gamma,
                                                  const float* __restrict__ beta,
                                                  const int* __restrict__ batch,
                                                  const int* __restrict__ gstart,
                                                  const int* __restrict__ gend,
                                                  const float* __restrict__ Wout,
                                                  float* __restrict__ out,
                                                  int store_hp) {
    __shared__ _Float16 Ls[2][16][136];   // 8704 B
    int tid = threadIdx.x;
    int wave = tid >> 6;
    int lane = tid & 63;
    int q = lane >> 4, l4 = lane & 15;
    int nbase = blockIdx.x * 32 + wave * 16;   // 32 | NN, no tail

    // wave-wide prefetch of the 16 nodes' CSR ranges + dis
    int l16 = lane & 15;
    int ev0 = rps[nbase + l16];
    int ev1 = rpe[nbase + l16];
    float dv = dis[nbase + l16];

    // ---- phase 1: gather 16 nodes into Ls, 8 nodes per round ----
    int g8 = lane >> 3;     // group 0..7 (owns one node per round)
    int l8 = lane & 7;      // lane in group: row bytes [l8*16, +16)
    const uint4* hp4 = (const uint4*)hpin;

#pragma unroll 1
    for (int r = 0; r < 2; r++) {
        int nl = r * 8 + g8;
        int e0 = __shfl(ev0, nl, 64);
        int e1 = __shfl(ev1, nl, 64);
        float dn = __shfl(dv, nl, 64);
        int node = nbase + nl;

        f32x2 a2[8];
#pragma unroll
        for (int j = 0; j < 8; j++) a2[j] = (f32x2){0.f, 0.f};

        uint4 sv = hp4[(size_t)node * 8 + l8];   // self row, issued early

        int e = e0;
        int pc0 = 0, pc1 = 0;
        if (e < e1) {                       // prime col pipeline (clamped)
            int m = e1 - 1;
            pc0 = col[e];
            pc1 = col[(e + 1 < e1) ? e + 1 : m];
        }
#pragma unroll 1
        for (; e + 1 < e1; e += 2) {
            int s0 = pc0, s1 = pc1;
            int n0 = e + 2, n1 = e + 3;
            pc0 = col[(n0 < e1) ? n0 : e0];   // next-iter cols overlap row loads
            pc1 = col[(n1 < e1) ? n1 : e0];
            uint4 v0 = hp4[(size_t)s0 * 8 + l8];
            uint4 v1 = hp4[(size_t)s1 * 8 + l8];
            acc_fp8x16(v0, a2);
            acc_fp8x16(v1, a2);
        }
        if (e < e1) {   // tail (1 edge): col already prefetched
            uint4 v = hp4[(size_t)pc0 * 8 + l8];
            acc_fp8x16(v, a2);
        }
        acc_fp8x16(sv, a2);   // self-loop

        f16x8 o0, o1;
#pragma unroll
        for (int j = 0; j < 4; j++) {
            o0[2 * j]     = (_Float16)(a2[j][0] * dn);
            o0[2 * j + 1] = (_Float16)(a2[j][1] * dn);
            o1[2 * j]     = (_Float16)(a2[4 + j][0] * dn);
            o1[2 * j + 1] = (_Float16)(a2[4 + j][1] * dn);
        }
        *(f16x8*)&Ls[wave][nl][l8 * 16] = o0;
        *(f16x8*)&Ls[wave][nl][l8 * 16 + 8] = o1;
    }

    // ---- phase 2: read A-fragments into registers, then GEMM + LN (Ls reused) ----
    f16x8 af[4];
#pragma unroll
    for (int ks = 0; ks < 4; ks++)
        af[ks] = *(const f16x8*)&Ls[wave][l4][ks * 32 + q * 8];

    float bb[8], gm[8], bt[8];
#pragma unroll
    for (int nt = 0; nt < 8; nt++) {
        bb[nt] = bias[nt * 16 + l4];
        gm[nt] = gamma[nt * 16 + l4];
        bt[nt] = beta[nt * 16 + l4];
    }

    const f16x8* wp8 = (const f16x8*)Wp;
    f32x4 acc[8];
#pragma unroll
    for (int nt = 0; nt < 8; nt++) {
        acc[nt] = (f32x4){0.f, 0.f, 0.f, 0.f};
#pragma unroll
        for (int ks = 0; ks < 4; ks++) {
            f16x8 bf = wp8[(ks * 8 + nt) * 64 + lane];
            acc[nt] = __builtin_amdgcn_mfma_f32_16x16x32_f16(af[ks], bf, acc[nt], 0, 0, 0);
        }
#pragma unroll
        for (int r = 0; r < 4; r++) acc[nt][r] += bb[nt];
    }

    float mu[4], rs[4];
#pragma unroll
    for (int r = 0; r < 4; r++) {
        float s = 0.f;
#pragma unroll
        for (int nt = 0; nt < 8; nt++) s += acc[nt][r];
#pragma unroll
        for (int off = 8; off > 0; off >>= 1) s += __shfl_xor(s, off, 64);
        mu[r] = s * (1.f / 128.f);
    }
#pragma unroll
    for (int r = 0; r < 4; r++) {
        float v = 0.f;
#pragma unroll
        for (int nt = 0; nt < 8; nt++) {
            float d = acc[nt][r] - mu[r];
            v += d * d;
        }
#pragma unroll
        for (int off = 8; off > 0; off >>= 1) v += __shfl_xor(v, off, 64);
        rs[r] = rsqrtf(v * (1.f / 128.f) + EPS);
    }

    // overwrite Ls with LN output (af already in registers)
#pragma unroll
    for (int nt = 0; nt < 8; nt++)
#pragma unroll
        for (int r = 0; r < 4; r++) {
            float o = fmaxf((acc[nt][r] - mu[r]) * rs[r] * gm[nt] + bt[nt], 0.f);
            Ls[wave][q * 4 + r][nt * 16 + l4] = (_Float16)o;
        }

    // epilogue
    const f16x8* hi8 = (const f16x8*)hin;
    f16x8* ho8 = (f16x8*)hout;
    int ck = lane & 15;
    if (store_hp) {
#pragma unroll
        for (int it = 0; it < 4; it++) {
            int c = it * 64 + lane;
            int rr = c >> 4;
            int row = nbase + rr;
            f16x8 ln = *(const f16x8*)&Ls[wave][rr][ck * 8];
            f16x8 res = hi8[(size_t)row * 16 + ck];
            float dn2 = __shfl(dv, rr, 64);
            f16x8 o;
            float hv[8];
#pragma unroll
            for (int j = 0; j < 8; j++) {
                float s = (float)ln[j] + (float)res[j];
                o[j] = (_Float16)s;
                hv[j] = s * dn2;
            }
            ho8[(size_t)row * 16 + ck] = o;
            hpout[(size_t)row * 16 + ck] = pack_fp8x8(hv);
        }
    } else {
        // fused global-mean-pool with segmented wave reduction
        float wv[8];
#pragma unroll
        for (int j = 0; j < 8; j++) wv[j] = Wout[ck * 8 + j];
        float pv[4];
#pragma unroll
        for (int it = 0; it < 4; it++) {
            int c = it * 64 + lane;
            int rr = c >> 4;
            int row = nbase + rr;
            f16x8 ln = *(const f16x8*)&Ls[wave][rr][ck * 8];
            f16x8 res = hi8[(size_t)row * 16 + ck];
            float p = 0.f;
#pragma unroll
            for (int j = 0; j < 8; j++)
                p += ((float)ln[j] + (float)res[j]) * wv[j];
            p += __shfl_xor(p, 1, 64);
            p += __shfl_xor(p, 2, 64);
            p += __shfl_xor(p, 4, 64);
            p += __shfl_xor(p, 8, 64);
            pv[it] = p;   // replicated across the 16-lane quarter
        }
        // redistribute: lane l16 takes row l16's value (src lane (l16&3)*16, slot l16>>2)
        int srcl = (l16 & 3) << 4;
        float s0 = __shfl(pv[0], srcl, 64);
        float s1 = __shfl(pv[1], srcl, 64);
        float s2 = __shfl(pv[2], srcl, 64);
        float s3 = __shfl(pv[3], srcl, 64);
        float v = (l16 < 4) ? s0 : (l16 < 8) ? s1 : (l16 < 12) ? s2 : s3;
        int g = batch[nbase + l16];
        // segmented inclusive sum (g ascending over rows; 16-lane groups)
#pragma unroll
        for (int off = 1; off < 16; off <<= 1) {
            float vn = __shfl(v, lane - off, 64);
            int gn = __shfl(g, lane - off, 64);
            if (l16 >= off && gn == g) v += vn;
        }
        int gnx = __shfl(g, lane + 1, 64);
        if (lane < 16 && ((l16 == 15) || (gnx != g))) {
            float inv = 1.f / (float)max(gend[g] - gstart[g], 1);
            atomicAdd(&out[g], v * inv);
        }
    }
}

// ---------------- launcher ----------------

extern "C" void kernel_launch(void* const* d_in, const int* in_sizes, int n_in,
                              void* d_out, int out_size, void* d_ws, size_t ws_size,
                              hipStream_t stream) {
    const float* x       = (const float*)d_in[0];
    const int*   edge    = (const int*)d_in[1];
    const int*   batch   = (const int*)d_in[2];
    const float* W_embed = (const float*)d_in[3];
    const float* b_embed = (const float*)d_in[4];
    const float* W_gnn   = (const float*)d_in[5];
    const float* b_gnn   = (const float*)d_in[6];
    const float* gamma   = (const float*)d_in[7];
    const float* beta    = (const float*)d_in[8];
    const float* W_out   = (const float*)d_in[9];
    const float* b_out   = (const float*)d_in[10];
    float* out = (float*)d_out;

    char* ws = (char*)d_ws;
    size_t off = 0;
    auto alloc = [&](size_t bytes) -> char* {
        char* p = ws + off;
        off += (bytes + 255) & ~(size_t)255;
        return p;
    };
    _Float16*     hh0  = (_Float16*)alloc((size_t)NN * H * 2);
    _Float16*     hh1  = (_Float16*)alloc((size_t)NN * H * 2);
    uint2*        hp0  = (uint2*)alloc((size_t)NN * H);       // fp8 gather copies
    uint2*        hp1  = (uint2*)alloc((size_t)NN * H);
    _Float16*     Wp   = (_Float16*)alloc((size_t)NL * 4 * 8 * 512 * 2);
    float*        dis  = (float*)alloc((size_t)NN * 4);
    int*          rps  = (int*)alloc((size_t)NN * 4);
    int*          rpe  = (int*)alloc((size_t)NN * 4);
    int*          col  = (int*)alloc((size_t)NBKT * CAP * 4);
    unsigned int* ebuf = (unsigned int*)alloc((size_t)NBKT * CAP * 4);
    int*          bfill = (int*)alloc((NBKT + 1) * 4);
    int*   gstart = (int*)alloc((size_t)NG * 4);
    int*   gend   = (int*)alloc((size_t)NG * 4);

    const int* srcp = edge;
    const int* dstp = edge + NE;

    hipMemsetAsync(bfill, 0, (NBKT + 1) * sizeof(int), stream);
    k_front<<<FRONT_B, 256, 0, stream>>>(W_gnn, Wp, out, b_out,
                                         batch, gstart, gend,
                                         srcp, dstp, bfill, ebuf,
                                         x, W_embed, b_embed, hh0);
    k_bcsr<<<NBKT * 4, 256, 0, stream>>>(ebuf, bfill, rps, rpe, col, dis, hh0, hp0);

    // ping-pong: L0 hh0->hh1, L1 hh1->hh0, L2 hh0->hh1, L3 fused-pool -> out
    _Float16* hb[2] = {hh0, hh1};
    uint2*    hp[2] = {hp0, hp1};
    for (int l = 0; l < NL; l++) {
        k_layer<<<(NN + 31) / 32, 128, 0, stream>>>(hb[l & 1], hb[(l & 1) ^ 1],
                                                    hp[l & 1], hp[(l & 1) ^ 1],
                                                    dis, rps, rpe, col,
                                                    Wp + (size_t)l * 4 * 8 * 512,
                                                    b_gnn + l * H, gamma + l * H, beta + l * H,
                                                    batch, gstart, gend, W_out, out,
                                                    (l != NL - 1) ? 1 : 0);
    }
}